// Round 1
// baseline (310.836 us; speedup 1.0000x reference)
//
#include <hip/hip_runtime.h>
#include <hip/hip_bf16.h>

#define TT 2048
#define CC 1024
#define HH 16
#define DD 64
#define FM 64      // feature dim M
#define NCH 32     // number of chunks
#define CL 64      // chunk length
#define N_QKV 3072
#define EPSV 1e-6f

// workspace offsets (in floats)
#define OFF_Q    0u
#define OFF_K    2097152u
#define OFF_V    4194304u
#define OFF_QP   6291456u
#define OFF_KP   8388608u
#define OFF_KV   0u          // reuses Q (q dead after k_feat)
#define OFF_SPRE 2097152u    // reuses K (k dead after k_feat)
#define OFF_KS   10485760u
#define OFF_ZPRE 10518528u
#define OFF_ATTN 10551296u
// total: 12,648,448 floats = 50.6 MB

#define FMA4x4(acc, a, b)                         \
  {                                               \
    float aa[4] = {a.x, a.y, a.z, a.w};           \
    float bb[4] = {b.x, b.y, b.z, b.w};           \
    _Pragma("unroll")                             \
    for (int i_ = 0; i_ < 4; ++i_)                \
      _Pragma("unroll")                           \
      for (int j_ = 0; j_ < 4; ++j_)              \
        acc[i_][j_] += aa[i_] * bb[j_];           \
  }

// ---------------- Kernel 1: qkv = x @ w_qkv + b, scattered to head layout ---
__global__ __launch_bounds__(256) void k_qkv(const float* __restrict__ x,
                                             const float* __restrict__ w,
                                             const float* __restrict__ bias,
                                             float* __restrict__ ws) {
  __shared__ float As[16][64];  // [k][m]
  __shared__ float Bs[16][64];  // [k][n]
  const int tid = threadIdx.x;
  const int tx = tid & 15, ty = tid >> 4;
  const int n0 = blockIdx.x * 64;
  const int m0 = blockIdx.y * 64;
  const int ar = tid >> 2;
  const int ak = (tid & 3) << 2;
  const int bk = tid >> 4;
  const int bn = (tid & 15) << 2;
  float acc[4][4] = {};
  for (int k0 = 0; k0 < CC; k0 += 16) {
    float4 av = *reinterpret_cast<const float4*>(&x[(m0 + ar) * CC + k0 + ak]);
    As[ak + 0][ar] = av.x; As[ak + 1][ar] = av.y;
    As[ak + 2][ar] = av.z; As[ak + 3][ar] = av.w;
    *reinterpret_cast<float4*>(&Bs[bk][bn]) =
        *reinterpret_cast<const float4*>(&w[(k0 + bk) * N_QKV + n0 + bn]);
    __syncthreads();
#pragma unroll
    for (int kk = 0; kk < 16; ++kk) {
      float4 a = *reinterpret_cast<const float4*>(&As[kk][ty * 4]);
      float4 b = *reinterpret_cast<const float4*>(&Bs[kk][tx * 4]);
      FMA4x4(acc, a, b);
    }
    __syncthreads();
  }
#pragma unroll
  for (int i = 0; i < 4; ++i) {
    int m = m0 + ty * 4 + i;
#pragma unroll
    for (int j = 0; j < 4; ++j) {
      int n = n0 + tx * 4 + j;
      float v = acc[i][j] + bias[n];
      int sel = n >> 10;           // 0=q 1=k 2=v
      int within = n & 1023;
      int h = within >> 6;
      int d = within & 63;
      ws[(unsigned)sel * 2097152u + ((unsigned)h * TT + m) * DD + d] = v;
    }
  }
}

// ---------------- Kernel 2: feature map q' = relu(q @ proj_h)/8 (and k') ----
__global__ __launch_bounds__(256) void k_feat(const float* __restrict__ proj,
                                              float* __restrict__ ws) {
  __shared__ float XsT[64][64];  // [d][t_local]
  __shared__ float Ps[64][64];   // [d][m]
  const int tid = threadIdx.x;
  const int t0 = blockIdx.x * 64;
  const int h = blockIdx.y;
  const int which = blockIdx.z;  // 0: q, 1: k
  const float* src = ws + (which == 0 ? OFF_Q : OFF_K) + (unsigned)h * TT * DD;
  float* dst = ws + (which == 0 ? OFF_QP : OFF_KP) + (unsigned)h * TT * FM;
#pragma unroll
  for (int rep = 0; rep < 4; ++rep) {
    int f = tid + rep * 256;
    int row = f >> 4;
    int q = (f & 15) << 2;
    float4 v = *reinterpret_cast<const float4*>(&src[(t0 + row) * DD + q]);
    XsT[q + 0][row] = v.x; XsT[q + 1][row] = v.y;
    XsT[q + 2][row] = v.z; XsT[q + 3][row] = v.w;
    *reinterpret_cast<float4*>(&Ps[row][q]) =
        *reinterpret_cast<const float4*>(&proj[((unsigned)h * DD + row) * FM + q]);
  }
  __syncthreads();
  const int tx = tid & 15, ty = tid >> 4;
  float acc[4][4] = {};
#pragma unroll 8
  for (int kk = 0; kk < 64; ++kk) {
    float4 a = *reinterpret_cast<const float4*>(&XsT[kk][ty * 4]);
    float4 b = *reinterpret_cast<const float4*>(&Ps[kk][tx * 4]);
    FMA4x4(acc, a, b);
  }
#pragma unroll
  for (int i = 0; i < 4; ++i) {
    int row = t0 + ty * 4 + i;
#pragma unroll
    for (int j = 0; j < 4; ++j) {
      int col = tx * 4 + j;
      float v = acc[i][j];
      v = v > 0.f ? v : 0.f;
      dst[(unsigned)row * FM + col] = v * 0.125f;
    }
  }
}

// ---------------- Kernel 3: per-chunk KV = k'^T @ v, Ksum = sum_t k' -------
__global__ __launch_bounds__(256) void k_chunkkv(float* __restrict__ ws) {
  __shared__ float Ks[64][64];  // [t][m]
  __shared__ float Vs[64][64];  // [t][d]
  const int tid = threadIdx.x;
  const int c = blockIdx.x, h = blockIdx.y;
  const int t0 = c * CL;
  const float* kp = ws + OFF_KP + (unsigned)h * TT * FM;
  const float* vv = ws + OFF_V + (unsigned)h * TT * DD;
#pragma unroll
  for (int rep = 0; rep < 4; ++rep) {
    int f = tid + rep * 256;
    int row = f >> 4, q = (f & 15) << 2;
    *reinterpret_cast<float4*>(&Ks[row][q]) =
        *reinterpret_cast<const float4*>(&kp[(t0 + row) * FM + q]);
    *reinterpret_cast<float4*>(&Vs[row][q]) =
        *reinterpret_cast<const float4*>(&vv[(t0 + row) * DD + q]);
  }
  __syncthreads();
  const int tx = tid & 15, ty = tid >> 4;
  float acc[4][4] = {};
#pragma unroll 8
  for (int t = 0; t < 64; ++t) {
    float4 a = *reinterpret_cast<const float4*>(&Ks[t][ty * 4]);  // m
    float4 b = *reinterpret_cast<const float4*>(&Vs[t][tx * 4]);  // d
    FMA4x4(acc, a, b);
  }
  float* kv = ws + OFF_KV + (unsigned)(h * NCH + c) * (FM * DD);
#pragma unroll
  for (int i = 0; i < 4; ++i)
#pragma unroll
    for (int j = 0; j < 4; ++j)
      kv[(unsigned)(ty * 4 + i) * DD + tx * 4 + j] = acc[i][j];
  if (tid < 64) {
    float s = 0.f;
    for (int t = 0; t < 64; ++t) s += Ks[t][tid];
    ws[OFF_KS + (unsigned)(h * NCH + c) * FM + tid] = s;
  }
}

// ---------------- Kernel 4: exclusive prefix over chunks -------------------
__global__ __launch_bounds__(256) void k_prefix(float* __restrict__ ws) {
  const int h = blockIdx.x, tid = threadIdx.x;
#pragma unroll
  for (int rep = 0; rep < 16; ++rep) {
    int e = tid + rep * 256;  // 0..4095
    float run = 0.f;
    for (int c = 0; c < NCH; ++c) {
      unsigned idx = (unsigned)(h * NCH + c) * 4096u + e;
      ws[OFF_SPRE + idx] = run;
      run += ws[OFF_KV + idx];
    }
  }
  if (tid < 64) {
    float run = 0.f;
    for (int c = 0; c < NCH; ++c) {
      unsigned idx = (unsigned)(h * NCH + c) * 64u + tid;
      ws[OFF_ZPRE + idx] = run;
      run += ws[OFF_KS + idx];
    }
  }
}

// ---------------- Kernel 5: per-(h,c) intra-chunk attention ----------------
__global__ __launch_bounds__(256) void k_attn(float* __restrict__ ws) {
  __shared__ float QT[64][64];  // [m][t]
  __shared__ float Vs[64][64];  // [t][d]
  __shared__ float Ss[64][64];  // [m][d]
  __shared__ float AT[64][64];  // first holds KT [m][t], then A^T [s][row]
  __shared__ float zs[64];
  __shared__ float norm_s[64];
  const int tid = threadIdx.x;
  const int c = blockIdx.x, h = blockIdx.y;
  const int t0 = c * CL;
  const float* qp = ws + OFF_QP + (unsigned)h * TT * FM;
  const float* kp = ws + OFF_KP + (unsigned)h * TT * FM;
  const float* vv = ws + OFF_V + (unsigned)h * TT * DD;
  const float* sp = ws + OFF_SPRE + (unsigned)(h * NCH + c) * 4096u;
  const float* zp = ws + OFF_ZPRE + (unsigned)(h * NCH + c) * 64u;
#pragma unroll
  for (int rep = 0; rep < 4; ++rep) {
    int f = tid + rep * 256;
    int row = f >> 4, q = (f & 15) << 2;
    float4 a = *reinterpret_cast<const float4*>(&qp[(t0 + row) * FM + q]);
    QT[q + 0][row] = a.x; QT[q + 1][row] = a.y;
    QT[q + 2][row] = a.z; QT[q + 3][row] = a.w;
    float4 b = *reinterpret_cast<const float4*>(&kp[(t0 + row) * FM + q]);
    AT[q + 0][row] = b.x; AT[q + 1][row] = b.y;  // KT staged in AT buffer
    AT[q + 2][row] = b.z; AT[q + 3][row] = b.w;
    *reinterpret_cast<float4*>(&Vs[row][q]) =
        *reinterpret_cast<const float4*>(&vv[(t0 + row) * DD + q]);
    *reinterpret_cast<float4*>(&Ss[row][q]) =
        *reinterpret_cast<const float4*>(&sp[row * DD + q]);
  }
  if (tid < 64) zs[tid] = zp[tid];
  __syncthreads();
  const int tx = tid & 15, ty = tid >> 4;
  // Phase A: A[row][s] = sum_m q'[row][m] k'[s][m]
  float accA[4][4] = {};
#pragma unroll 8
  for (int m = 0; m < 64; ++m) {
    float4 a = *reinterpret_cast<const float4*>(&QT[m][ty * 4]);
    float4 b = *reinterpret_cast<const float4*>(&AT[m][tx * 4]);
    FMA4x4(accA, a, b);
  }
  __syncthreads();  // everyone done reading KT
#pragma unroll
  for (int i = 0; i < 4; ++i)
#pragma unroll
    for (int j = 0; j < 4; ++j) {
      int row = ty * 4 + i, s = tx * 4 + j;
      AT[s][row] = (s <= row) ? accA[i][j] : 0.f;  // causal mask, transposed
    }
  __syncthreads();
  if (tid < 64) {
    int row = tid;
    float nr = 0.f;
    for (int s = 0; s < 64; ++s) nr += AT[s][row];
    float qz = 0.f;
    for (int m = 0; m < 64; ++m) qz += QT[m][row] * zs[m];
    norm_s[row] = nr + qz + EPSV;
  }
  __syncthreads();
  // Phase B: ctx[row][d] = sum_m q'[row][m] S[m][d] + sum_s A[row][s] v[s][d]
  float acc[4][4] = {};
#pragma unroll 8
  for (int m = 0; m < 64; ++m) {
    float4 a = *reinterpret_cast<const float4*>(&QT[m][ty * 4]);
    float4 b = *reinterpret_cast<const float4*>(&Ss[m][tx * 4]);
    FMA4x4(acc, a, b);
  }
#pragma unroll 8
  for (int s = 0; s < 64; ++s) {
    float4 a = *reinterpret_cast<const float4*>(&AT[s][ty * 4]);
    float4 b = *reinterpret_cast<const float4*>(&Vs[s][tx * 4]);
    FMA4x4(acc, a, b);
  }
  float* attn = ws + OFF_ATTN;
#pragma unroll
  for (int i = 0; i < 4; ++i) {
    int row = ty * 4 + i;
    float inv = 1.0f / norm_s[row];
#pragma unroll
    for (int j = 0; j < 4; ++j) {
      int d = tx * 4 + j;
      attn[(unsigned)(t0 + row) * CC + h * DD + d] = acc[i][j] * inv;
    }
  }
}

// ---------------- Kernel 6: out = attn @ w_out + b_out ---------------------
__global__ __launch_bounds__(256) void k_out(const float* __restrict__ a,
                                             const float* __restrict__ w,
                                             const float* __restrict__ bias,
                                             float* __restrict__ out) {
  __shared__ float As[16][64];
  __shared__ float Bs[16][64];
  const int tid = threadIdx.x;
  const int tx = tid & 15, ty = tid >> 4;
  const int n0 = blockIdx.x * 64;
  const int m0 = blockIdx.y * 64;
  const int ar = tid >> 2;
  const int ak = (tid & 3) << 2;
  const int bk = tid >> 4;
  const int bn = (tid & 15) << 2;
  float acc[4][4] = {};
  for (int k0 = 0; k0 < CC; k0 += 16) {
    float4 av = *reinterpret_cast<const float4*>(&a[(m0 + ar) * CC + k0 + ak]);
    As[ak + 0][ar] = av.x; As[ak + 1][ar] = av.y;
    As[ak + 2][ar] = av.z; As[ak + 3][ar] = av.w;
    *reinterpret_cast<float4*>(&Bs[bk][bn]) =
        *reinterpret_cast<const float4*>(&w[(k0 + bk) * CC + n0 + bn]);
    __syncthreads();
#pragma unroll
    for (int kk = 0; kk < 16; ++kk) {
      float4 av2 = *reinterpret_cast<const float4*>(&As[kk][ty * 4]);
      float4 bv2 = *reinterpret_cast<const float4*>(&Bs[kk][tx * 4]);
      FMA4x4(acc, av2, bv2);
    }
    __syncthreads();
  }
#pragma unroll
  for (int i = 0; i < 4; ++i) {
    int m = m0 + ty * 4 + i;
#pragma unroll
    for (int j = 0; j < 4; ++j) {
      int n = n0 + tx * 4 + j;
      out[(unsigned)m * CC + n] = acc[i][j] + bias[n];
    }
  }
}

extern "C" void kernel_launch(void* const* d_in, const int* in_sizes, int n_in,
                              void* d_out, int out_size, void* d_ws, size_t ws_size,
                              hipStream_t stream) {
  const float* x = (const float*)d_in[0];
  const float* w_qkv = (const float*)d_in[1];
  const float* b_qkv = (const float*)d_in[2];
  const float* w_out = (const float*)d_in[3];
  const float* b_out = (const float*)d_in[4];
  const float* proj = (const float*)d_in[5];
  float* ws = (float*)d_ws;
  float* out = (float*)d_out;
  dim3 blk(256, 1, 1);
  k_qkv<<<dim3(N_QKV / 64, TT / 64), blk, 0, stream>>>(x, w_qkv, b_qkv, ws);
  k_feat<<<dim3(TT / 64, HH, 2), blk, 0, stream>>>(proj, ws);
  k_chunkkv<<<dim3(NCH, HH), blk, 0, stream>>>(ws);
  k_prefix<<<dim3(HH), blk, 0, stream>>>(ws);
  k_attn<<<dim3(NCH, HH), blk, 0, stream>>>(ws);
  k_out<<<dim3(CC / 64, TT / 64), blk, 0, stream>>>(ws + OFF_ATTN, w_out, b_out, out);
}

// Round 2
// 116.096 us; speedup vs baseline: 2.6774x; 2.6774x over previous
//
#include <hip/hip_runtime.h>
#include <hip/hip_bf16.h>

#define TT 2048
#define CC 1024
#define HH 16
#define DD 64
#define FM 64
#define NCH 32
#define CL 64
#define N_QKV 3072
#define EPSV 1e-6f

// fp32 workspace offsets (float units)
#define OFF_Q    0u
#define OFF_K    2097152u
#define OFF_V    4194304u
#define OFF_QP   6291456u
#define OFF_KP   8388608u
#define OFF_KV   0u          // reuses Q (dead after k_feat)
#define OFF_SPRE 2097152u    // reuses K (dead after k_feat)
#define OFF_KS   10485760u
#define OFF_ZPRE 10518528u
#define OFF_BF16 10551296u   // bf16 region starts here (float units)
// bf16 region (ushort units, relative to base):
//   XBF  @ 0        (2,097,152)  -- x in bf16; later reused as ATTN bf16
//   WQT  @ 2097152  (3,145,728)  -- w_qkv^T bf16 [3072][1024]
//   WOT  @ 5242880  (1,048,576)  -- w_out^T bf16 [1024][1024]
// total ws = 54.8 MB

typedef __attribute__((ext_vector_type(8))) short bf16x8;
typedef __attribute__((ext_vector_type(4))) float f32x4;
typedef __attribute__((ext_vector_type(4))) unsigned short u16x4;

__device__ __forceinline__ unsigned short f2bf(float f) {
  unsigned int u = __float_as_uint(f);
  u = (u + 0x7fffu + ((u >> 16) & 1u)) >> 16;
  return (unsigned short)u;
}

__device__ __forceinline__ void gload16(const void* g, void* l) {
  __builtin_amdgcn_global_load_lds(
      (const __attribute__((address_space(1))) unsigned int*)g,
      (__attribute__((address_space(3))) unsigned int*)l, 16, 0, 0);
}

#define FMA4x4(acc, a, b)                         \
  {                                               \
    float aa[4] = {a.x, a.y, a.z, a.w};           \
    float bb[4] = {b.x, b.y, b.z, b.w};           \
    _Pragma("unroll")                             \
    for (int i_ = 0; i_ < 4; ++i_)                \
      _Pragma("unroll")                           \
      for (int j_ = 0; j_ < 4; ++j_)              \
        acc[i_][j_] += aa[i_] * bb[j_];           \
  }

// ---------------- fp32 -> bf16 elementwise (x) -----------------------------
__global__ __launch_bounds__(256) void k_f32_to_bf16(const float* __restrict__ src,
                                                     unsigned short* __restrict__ dst) {
  unsigned i = blockIdx.x * 256u + threadIdx.x;
  float4 v = *reinterpret_cast<const float4*>(&src[i * 4u]);
  u16x4 o;
  o[0] = f2bf(v.x); o[1] = f2bf(v.y); o[2] = f2bf(v.z); o[3] = f2bf(v.w);
  *reinterpret_cast<u16x4*>(&dst[i * 4u]) = o;
}

// ---------------- fp32 [K][N] -> bf16 [N][K] transpose ---------------------
__global__ __launch_bounds__(256) void k_transpose_bf(const float* __restrict__ src,
                                                      unsigned short* __restrict__ dst,
                                                      int K, int N) {
  __shared__ float T[64][68];
  const int tid = threadIdx.x;
  const int n0 = blockIdx.x * 64, k0 = blockIdx.y * 64;
#pragma unroll
  for (int it = 0; it < 4; ++it) {
    int f = tid + it * 256;
    int r = f >> 4, c4 = (f & 15) * 4;
    float4 v = *reinterpret_cast<const float4*>(&src[(unsigned)(k0 + r) * N + n0 + c4]);
    T[r][c4 + 0] = v.x; T[r][c4 + 1] = v.y;
    T[r][c4 + 2] = v.z; T[r][c4 + 3] = v.w;
  }
  __syncthreads();
#pragma unroll
  for (int it = 0; it < 4; ++it) {
    int f = tid + it * 256;
    int nl = f >> 4, kq = (f & 15) * 4;
    u16x4 o;
#pragma unroll
    for (int j = 0; j < 4; ++j) o[j] = f2bf(T[kq + j][nl]);
    *reinterpret_cast<u16x4*>(&dst[(unsigned)(n0 + nl) * K + k0 + kq]) = o;
  }
}

// ---------------- shared 128x128 MFMA GEMM core ----------------------------
// A [M][K] bf16 row-major, BT [N][K] bf16 row-major. BK=64, 4 waves.
// LDS XOR-swizzle: slot s of row r holds global kchunk s^(r&7) (8 bf16/chunk);
// achieved by pre-swizzling the per-lane global source of global_load_lds.
__device__ __forceinline__ void gemm_core_128(
    const unsigned short* __restrict__ A, const unsigned short* __restrict__ BT,
    int K, int m0, int n0, unsigned short* As, unsigned short* Bs,
    f32x4 acc[4][4]) {
  const int tid = threadIdx.x;
  const int lane = tid & 63;
  const int w = tid >> 6;
  const int wm = w >> 1, wn = w & 1;
  const int l8 = lane >> 3, l7 = lane & 7;
  const int kcg = (l7 ^ l8) * 8;  // pre-swizzled source k-chunk
  for (int k0 = 0; k0 < K; k0 += 64) {
    if (k0) __syncthreads();
#pragma unroll
    for (int j = 0; j < 4; ++j) {
      const int inst = w * 4 + j;
      const int row = inst * 8 + l8;
      gload16(&A[(unsigned)(m0 + row) * K + k0 + kcg], &As[inst * 512]);
      gload16(&BT[(unsigned)(n0 + row) * K + k0 + kcg], &Bs[inst * 512]);
    }
    __syncthreads();
#pragma unroll
    for (int kk = 0; kk < 2; ++kk) {
      bf16x8 af[4], bg[4];
#pragma unroll
      for (int i = 0; i < 4; ++i) {
        const int r = wm * 64 + i * 16 + (lane & 15);
        const int slot = (kk * 4 + (lane >> 4)) ^ (r & 7);
        af[i] = *reinterpret_cast<const bf16x8*>(&As[r * 64 + slot * 8]);
      }
#pragma unroll
      for (int j = 0; j < 4; ++j) {
        const int r = wn * 64 + j * 16 + (lane & 15);
        const int slot = (kk * 4 + (lane >> 4)) ^ (r & 7);
        bg[j] = *reinterpret_cast<const bf16x8*>(&Bs[r * 64 + slot * 8]);
      }
#pragma unroll
      for (int i = 0; i < 4; ++i)
#pragma unroll
        for (int j = 0; j < 4; ++j)
          acc[i][j] = __builtin_amdgcn_mfma_f32_16x16x32_bf16(af[i], bg[j],
                                                              acc[i][j], 0, 0, 0);
    }
  }
}

// ---------------- Kernel 1: qkv = x @ w_qkv + b (MFMA), scatter to heads ---
__global__ __launch_bounds__(256) void k_qkv_mfma(const unsigned short* __restrict__ Xbf,
                                                  const unsigned short* __restrict__ WqT,
                                                  const float* __restrict__ bias,
                                                  float* __restrict__ ws) {
  __shared__ unsigned short As[128 * 64];
  __shared__ unsigned short Bs[128 * 64];
  f32x4 acc[4][4] = {};
  gemm_core_128(Xbf, WqT, CC, blockIdx.y * 128, blockIdx.x * 128, As, Bs, acc);
  const int lane = threadIdx.x & 63, w = threadIdx.x >> 6;
  const int m0 = blockIdx.y * 128 + (w >> 1) * 64;
  const int n0 = blockIdx.x * 128 + (w & 1) * 64;
#pragma unroll
  for (int i = 0; i < 4; ++i) {
#pragma unroll
    for (int j = 0; j < 4; ++j) {
      const int n = n0 + j * 16 + (lane & 15);
      const float bv = bias[n];
      const int sel = n >> 10, within = n & 1023;
      const int h = within >> 6, d = within & 63;
      float* dst = ws + (unsigned)sel * 2097152u + (unsigned)h * TT * DD + d;
#pragma unroll
      for (int r = 0; r < 4; ++r) {
        const int m = m0 + i * 16 + (lane >> 4) * 4 + r;
        dst[(unsigned)m * DD] = acc[i][j][r] + bv;
      }
    }
  }
}

// ---------------- Kernel 6: out = attn @ w_out + b (MFMA) ------------------
__global__ __launch_bounds__(256) void k_out_mfma(const unsigned short* __restrict__ Abf,
                                                  const unsigned short* __restrict__ WoT,
                                                  const float* __restrict__ bias,
                                                  float* __restrict__ out) {
  __shared__ unsigned short As[128 * 64];
  __shared__ unsigned short Bs[128 * 64];
  f32x4 acc[4][4] = {};
  gemm_core_128(Abf, WoT, CC, blockIdx.y * 128, blockIdx.x * 128, As, Bs, acc);
  const int lane = threadIdx.x & 63, w = threadIdx.x >> 6;
  const int m0 = blockIdx.y * 128 + (w >> 1) * 64;
  const int n0 = blockIdx.x * 128 + (w & 1) * 64;
#pragma unroll
  for (int i = 0; i < 4; ++i) {
#pragma unroll
    for (int j = 0; j < 4; ++j) {
      const int n = n0 + j * 16 + (lane & 15);
      const float bv = bias[n];
#pragma unroll
      for (int r = 0; r < 4; ++r) {
        const int m = m0 + i * 16 + (lane >> 4) * 4 + r;
        out[(unsigned)m * CC + n] = acc[i][j][r] + bv;
      }
    }
  }
}

// ---------------- Kernel 2: feature map q' = relu(q @ proj_h)/8 ------------
__global__ __launch_bounds__(256) void k_feat(const float* __restrict__ proj,
                                              float* __restrict__ ws) {
  __shared__ float XsT[64][64];
  __shared__ float Ps[64][64];
  const int tid = threadIdx.x;
  const int t0 = blockIdx.x * 64;
  const int h = blockIdx.y;
  const int which = blockIdx.z;
  const float* src = ws + (which == 0 ? OFF_Q : OFF_K) + (unsigned)h * TT * DD;
  float* dst = ws + (which == 0 ? OFF_QP : OFF_KP) + (unsigned)h * TT * FM;
#pragma unroll
  for (int rep = 0; rep < 4; ++rep) {
    int f = tid + rep * 256;
    int row = f >> 4;
    int q = (f & 15) << 2;
    float4 v = *reinterpret_cast<const float4*>(&src[(t0 + row) * DD + q]);
    XsT[q + 0][row] = v.x; XsT[q + 1][row] = v.y;
    XsT[q + 2][row] = v.z; XsT[q + 3][row] = v.w;
    *reinterpret_cast<float4*>(&Ps[row][q]) =
        *reinterpret_cast<const float4*>(&proj[((unsigned)h * DD + row) * FM + q]);
  }
  __syncthreads();
  const int tx = tid & 15, ty = tid >> 4;
  float acc[4][4] = {};
#pragma unroll 8
  for (int kk = 0; kk < 64; ++kk) {
    float4 a = *reinterpret_cast<const float4*>(&XsT[kk][ty * 4]);
    float4 b = *reinterpret_cast<const float4*>(&Ps[kk][tx * 4]);
    FMA4x4(acc, a, b);
  }
#pragma unroll
  for (int i = 0; i < 4; ++i) {
    int row = t0 + ty * 4 + i;
#pragma unroll
    for (int j = 0; j < 4; ++j) {
      int col = tx * 4 + j;
      float v = acc[i][j];
      v = v > 0.f ? v : 0.f;
      dst[(unsigned)row * FM + col] = v * 0.125f;
    }
  }
}

// ---------------- Kernel 3: per-chunk KV = k'^T @ v, Ksum ------------------
__global__ __launch_bounds__(256) void k_chunkkv(float* __restrict__ ws) {
  __shared__ float Ks[64][64];
  __shared__ float Vs[64][64];
  const int tid = threadIdx.x;
  const int c = blockIdx.x, h = blockIdx.y;
  const int t0 = c * CL;
  const float* kp = ws + OFF_KP + (unsigned)h * TT * FM;
  const float* vv = ws + OFF_V + (unsigned)h * TT * DD;
#pragma unroll
  for (int rep = 0; rep < 4; ++rep) {
    int f = tid + rep * 256;
    int row = f >> 4, q = (f & 15) << 2;
    *reinterpret_cast<float4*>(&Ks[row][q]) =
        *reinterpret_cast<const float4*>(&kp[(t0 + row) * FM + q]);
    *reinterpret_cast<float4*>(&Vs[row][q]) =
        *reinterpret_cast<const float4*>(&vv[(t0 + row) * DD + q]);
  }
  __syncthreads();
  const int tx = tid & 15, ty = tid >> 4;
  float acc[4][4] = {};
#pragma unroll 8
  for (int t = 0; t < 64; ++t) {
    float4 a = *reinterpret_cast<const float4*>(&Ks[t][ty * 4]);
    float4 b = *reinterpret_cast<const float4*>(&Vs[t][tx * 4]);
    FMA4x4(acc, a, b);
  }
  float* kv = ws + OFF_KV + (unsigned)(h * NCH + c) * (FM * DD);
#pragma unroll
  for (int i = 0; i < 4; ++i)
#pragma unroll
    for (int j = 0; j < 4; ++j)
      kv[(unsigned)(ty * 4 + i) * DD + tx * 4 + j] = acc[i][j];
  if (tid < 64) {
    float s = 0.f;
    for (int t = 0; t < 64; ++t) s += Ks[t][tid];
    ws[OFF_KS + (unsigned)(h * NCH + c) * FM + tid] = s;
  }
}

// ---------------- Kernel 4: exclusive prefix over chunks -------------------
__global__ __launch_bounds__(256) void k_prefix(float* __restrict__ ws) {
  const int h = blockIdx.x, tid = threadIdx.x;
#pragma unroll
  for (int rep = 0; rep < 16; ++rep) {
    int e = tid + rep * 256;
    float run = 0.f;
    for (int c = 0; c < NCH; ++c) {
      unsigned idx = (unsigned)(h * NCH + c) * 4096u + e;
      ws[OFF_SPRE + idx] = run;
      run += ws[OFF_KV + idx];
    }
  }
  if (tid < 64) {
    float run = 0.f;
    for (int c = 0; c < NCH; ++c) {
      unsigned idx = (unsigned)(h * NCH + c) * 64u + tid;
      ws[OFF_ZPRE + idx] = run;
      run += ws[OFF_KS + idx];
    }
  }
}

// ---------------- Kernel 5: per-(h,c) intra-chunk attention ----------------
__global__ __launch_bounds__(256) void k_attn(float* __restrict__ ws,
                                              unsigned short* __restrict__ attnb) {
  __shared__ float QT[64][64];
  __shared__ float Vs[64][64];
  __shared__ float Ss[64][64];
  __shared__ float AT[64][64];
  __shared__ float zs[64];
  __shared__ float norm_s[64];
  const int tid = threadIdx.x;
  const int c = blockIdx.x, h = blockIdx.y;
  const int t0 = c * CL;
  const float* qp = ws + OFF_QP + (unsigned)h * TT * FM;
  const float* kp = ws + OFF_KP + (unsigned)h * TT * FM;
  const float* vv = ws + OFF_V + (unsigned)h * TT * DD;
  const float* sp = ws + OFF_SPRE + (unsigned)(h * NCH + c) * 4096u;
  const float* zp = ws + OFF_ZPRE + (unsigned)(h * NCH + c) * 64u;
#pragma unroll
  for (int rep = 0; rep < 4; ++rep) {
    int f = tid + rep * 256;
    int row = f >> 4, q = (f & 15) << 2;
    float4 a = *reinterpret_cast<const float4*>(&qp[(t0 + row) * FM + q]);
    QT[q + 0][row] = a.x; QT[q + 1][row] = a.y;
    QT[q + 2][row] = a.z; QT[q + 3][row] = a.w;
    float4 b = *reinterpret_cast<const float4*>(&kp[(t0 + row) * FM + q]);
    AT[q + 0][row] = b.x; AT[q + 1][row] = b.y;
    AT[q + 2][row] = b.z; AT[q + 3][row] = b.w;
    *reinterpret_cast<float4*>(&Vs[row][q]) =
        *reinterpret_cast<const float4*>(&vv[(t0 + row) * DD + q]);
    *reinterpret_cast<float4*>(&Ss[row][q]) =
        *reinterpret_cast<const float4*>(&sp[row * DD + q]);
  }
  if (tid < 64) zs[tid] = zp[tid];
  __syncthreads();
  const int tx = tid & 15, ty = tid >> 4;
  float accA[4][4] = {};
#pragma unroll 8
  for (int m = 0; m < 64; ++m) {
    float4 a = *reinterpret_cast<const float4*>(&QT[m][ty * 4]);
    float4 b = *reinterpret_cast<const float4*>(&AT[m][tx * 4]);
    FMA4x4(accA, a, b);
  }
  __syncthreads();
#pragma unroll
  for (int i = 0; i < 4; ++i)
#pragma unroll
    for (int j = 0; j < 4; ++j) {
      int row = ty * 4 + i, s = tx * 4 + j;
      AT[s][row] = (s <= row) ? accA[i][j] : 0.f;
    }
  __syncthreads();
  if (tid < 64) {
    int row = tid;
    float nr = 0.f;
    for (int s = 0; s < 64; ++s) nr += AT[s][row];
    float qz = 0.f;
    for (int m = 0; m < 64; ++m) qz += QT[m][row] * zs[m];
    norm_s[row] = nr + qz + EPSV;
  }
  __syncthreads();
  float acc[4][4] = {};
#pragma unroll 8
  for (int m = 0; m < 64; ++m) {
    float4 a = *reinterpret_cast<const float4*>(&QT[m][ty * 4]);
    float4 b = *reinterpret_cast<const float4*>(&Ss[m][tx * 4]);
    FMA4x4(acc, a, b);
  }
#pragma unroll 8
  for (int s = 0; s < 64; ++s) {
    float4 a = *reinterpret_cast<const float4*>(&AT[s][ty * 4]);
    float4 b = *reinterpret_cast<const float4*>(&Vs[s][tx * 4]);
    FMA4x4(acc, a, b);
  }
#pragma unroll
  for (int i = 0; i < 4; ++i) {
    int row = ty * 4 + i;
    float inv = 1.0f / norm_s[row];
#pragma unroll
    for (int j = 0; j < 4; ++j) {
      int d = tx * 4 + j;
      attnb[(unsigned)(t0 + row) * CC + h * DD + d] = f2bf(acc[i][j] * inv);
    }
  }
}

extern "C" void kernel_launch(void* const* d_in, const int* in_sizes, int n_in,
                              void* d_out, int out_size, void* d_ws, size_t ws_size,
                              hipStream_t stream) {
  const float* x = (const float*)d_in[0];
  const float* w_qkv = (const float*)d_in[1];
  const float* b_qkv = (const float*)d_in[2];
  const float* w_out = (const float*)d_in[3];
  const float* b_out = (const float*)d_in[4];
  const float* proj = (const float*)d_in[5];
  float* ws = (float*)d_ws;
  float* out = (float*)d_out;
  unsigned short* xbf = (unsigned short*)(ws + OFF_BF16);
  unsigned short* wqT = xbf + 2097152u;
  unsigned short* woT = wqT + 3145728u;
  unsigned short* attnb = xbf;  // alias: x_bf16 dead after k_qkv_mfma
  dim3 blk(256, 1, 1);
  k_f32_to_bf16<<<dim3(2048), blk, 0, stream>>>(x, xbf);
  k_transpose_bf<<<dim3(N_QKV / 64, CC / 64), blk, 0, stream>>>(w_qkv, wqT, CC, N_QKV);
  k_transpose_bf<<<dim3(CC / 64, CC / 64), blk, 0, stream>>>(w_out, woT, CC, CC);
  k_qkv_mfma<<<dim3(N_QKV / 128, TT / 128), blk, 0, stream>>>(xbf, wqT, b_qkv, ws);
  k_feat<<<dim3(TT / 64, HH, 2), blk, 0, stream>>>(proj, ws);
  k_chunkkv<<<dim3(NCH, HH), blk, 0, stream>>>(ws);
  k_prefix<<<dim3(HH), blk, 0, stream>>>(ws);
  k_attn<<<dim3(NCH, HH), blk, 0, stream>>>(ws, attnb);
  k_out_mfma<<<dim3(CC / 128, TT / 128), blk, 0, stream>>>(attnb, woT, b_out, out);
}

// Round 3
// 105.214 us; speedup vs baseline: 2.9543x; 1.1034x over previous
//
#include <hip/hip_runtime.h>
#include <hip/hip_bf16.h>

#define TT 2048
#define CC 1024
#define HH 16
#define DD 64
#define FM 64
#define NCH 32
#define CL 64
#define N_QKV 3072
#define EPSV 1e-6f

// fp32 workspace offsets (float units)
#define OFF_Q    0u
#define OFF_K    2097152u
#define OFF_V    4194304u
#define OFF_QP   6291456u
#define OFF_KP   8388608u
#define OFF_KV   0u          // reuses Q (dead after k_feat)
#define OFF_SPRE 2097152u    // reuses K (dead after k_feat)
#define OFF_KS   10485760u
#define OFF_ZPRE 10518528u
#define OFF_BF16 10551296u   // bf16 region starts here (float units)
// bf16 region (ushort units, relative to base):
//   XBF  @ 0        (2,097,152)  -- x in bf16; later reused as ATTN bf16
//   WQT  @ 2097152  (3,145,728)  -- w_qkv^T bf16 [3072][1024]
//   WOT  @ 5242880  (1,048,576)  -- w_out^T bf16 [1024][1024]

typedef __attribute__((ext_vector_type(8))) short bf16x8;
typedef __attribute__((ext_vector_type(4))) float f32x4;
typedef __attribute__((ext_vector_type(4))) unsigned short u16x4;

__device__ __forceinline__ unsigned short f2bf(float f) {
  unsigned int u = __float_as_uint(f);
  u = (u + 0x7fffu + ((u >> 16) & 1u)) >> 16;
  return (unsigned short)u;
}

__device__ __forceinline__ void gload16(const void* g, void* l) {
  __builtin_amdgcn_global_load_lds(
      (const __attribute__((address_space(1))) unsigned int*)g,
      (__attribute__((address_space(3))) unsigned int*)l, 16, 0, 0);
}

#define FMA4x4(acc, a, b)                         \
  {                                               \
    float aa[4] = {a.x, a.y, a.z, a.w};           \
    float bb[4] = {b.x, b.y, b.z, b.w};           \
    _Pragma("unroll")                             \
    for (int i_ = 0; i_ < 4; ++i_)                \
      _Pragma("unroll")                           \
      for (int j_ = 0; j_ < 4; ++j_)              \
        acc[i_][j_] += aa[i_] * bb[j_];           \
  }

// ---------------- fp32 -> bf16 elementwise (x) -----------------------------
__global__ __launch_bounds__(256) void k_f32_to_bf16(const float* __restrict__ src,
                                                     unsigned short* __restrict__ dst) {
  unsigned i = blockIdx.x * 256u + threadIdx.x;
  float4 v = *reinterpret_cast<const float4*>(&src[i * 4u]);
  u16x4 o;
  o[0] = f2bf(v.x); o[1] = f2bf(v.y); o[2] = f2bf(v.z); o[3] = f2bf(v.w);
  *reinterpret_cast<u16x4*>(&dst[i * 4u]) = o;
}

// ---------------- fp32 [K][N] -> bf16 [N][K] transpose ---------------------
__global__ __launch_bounds__(256) void k_transpose_bf(const float* __restrict__ src,
                                                      unsigned short* __restrict__ dst,
                                                      int K, int N) {
  __shared__ float T[64][68];
  const int tid = threadIdx.x;
  const int n0 = blockIdx.x * 64, k0 = blockIdx.y * 64;
#pragma unroll
  for (int it = 0; it < 4; ++it) {
    int f = tid + it * 256;
    int r = f >> 4, c4 = (f & 15) * 4;
    float4 v = *reinterpret_cast<const float4*>(&src[(unsigned)(k0 + r) * N + n0 + c4]);
    T[r][c4 + 0] = v.x; T[r][c4 + 1] = v.y;
    T[r][c4 + 2] = v.z; T[r][c4 + 3] = v.w;
  }
  __syncthreads();
#pragma unroll
  for (int it = 0; it < 4; ++it) {
    int f = tid + it * 256;
    int nl = f >> 4, kq = (f & 15) * 4;
    u16x4 o;
#pragma unroll
    for (int j = 0; j < 4; ++j) o[j] = f2bf(T[kq + j][nl]);
    *reinterpret_cast<u16x4*>(&dst[(unsigned)(n0 + nl) * K + k0 + kq]) = o;
  }
}

// ---------------- shared 128x128 MFMA GEMM core ----------------------------
__device__ __forceinline__ void gemm_core_128(
    const unsigned short* __restrict__ A, const unsigned short* __restrict__ BT,
    int K, int m0, int n0, unsigned short* As, unsigned short* Bs,
    f32x4 acc[4][4]) {
  const int tid = threadIdx.x;
  const int lane = tid & 63;
  const int w = tid >> 6;
  const int wm = w >> 1, wn = w & 1;
  const int l8 = lane >> 3, l7 = lane & 7;
  const int kcg = (l7 ^ l8) * 8;  // pre-swizzled source k-chunk
  for (int k0 = 0; k0 < K; k0 += 64) {
    if (k0) __syncthreads();
#pragma unroll
    for (int j = 0; j < 4; ++j) {
      const int inst = w * 4 + j;
      const int row = inst * 8 + l8;
      gload16(&A[(unsigned)(m0 + row) * K + k0 + kcg], &As[inst * 512]);
      gload16(&BT[(unsigned)(n0 + row) * K + k0 + kcg], &Bs[inst * 512]);
    }
    __syncthreads();
#pragma unroll
    for (int kk = 0; kk < 2; ++kk) {
      bf16x8 af[4], bg[4];
#pragma unroll
      for (int i = 0; i < 4; ++i) {
        const int r = wm * 64 + i * 16 + (lane & 15);
        const int slot = (kk * 4 + (lane >> 4)) ^ (r & 7);
        af[i] = *reinterpret_cast<const bf16x8*>(&As[r * 64 + slot * 8]);
      }
#pragma unroll
      for (int j = 0; j < 4; ++j) {
        const int r = wn * 64 + j * 16 + (lane & 15);
        const int slot = (kk * 4 + (lane >> 4)) ^ (r & 7);
        bg[j] = *reinterpret_cast<const bf16x8*>(&Bs[r * 64 + slot * 8]);
      }
#pragma unroll
      for (int i = 0; i < 4; ++i)
#pragma unroll
        for (int j = 0; j < 4; ++j)
          acc[i][j] = __builtin_amdgcn_mfma_f32_16x16x32_bf16(af[i], bg[j],
                                                              acc[i][j], 0, 0, 0);
    }
  }
}

// ---------------- Kernel 1: qkv = x @ w_qkv + b (MFMA), scatter to heads ---
__global__ __launch_bounds__(256) void k_qkv_mfma(const unsigned short* __restrict__ Xbf,
                                                  const unsigned short* __restrict__ WqT,
                                                  const float* __restrict__ bias,
                                                  float* __restrict__ ws) {
  __shared__ unsigned short As[128 * 64];
  __shared__ unsigned short Bs[128 * 64];
  f32x4 acc[4][4] = {};
  gemm_core_128(Xbf, WqT, CC, blockIdx.y * 128, blockIdx.x * 128, As, Bs, acc);
  const int lane = threadIdx.x & 63, w = threadIdx.x >> 6;
  const int m0 = blockIdx.y * 128 + (w >> 1) * 64;
  const int n0 = blockIdx.x * 128 + (w & 1) * 64;
#pragma unroll
  for (int i = 0; i < 4; ++i) {
#pragma unroll
    for (int j = 0; j < 4; ++j) {
      const int n = n0 + j * 16 + (lane & 15);
      const float bv = bias[n];
      const int sel = n >> 10, within = n & 1023;
      const int h = within >> 6, d = within & 63;
      float* dst = ws + (unsigned)sel * 2097152u + (unsigned)h * TT * DD + d;
#pragma unroll
      for (int r = 0; r < 4; ++r) {
        const int m = m0 + i * 16 + (lane >> 4) * 4 + r;
        dst[(unsigned)m * DD] = acc[i][j][r] + bv;
      }
    }
  }
}

// ---------------- Kernel 6: out = attn @ w_out + b (MFMA) ------------------
__global__ __launch_bounds__(256) void k_out_mfma(const unsigned short* __restrict__ Abf,
                                                  const unsigned short* __restrict__ WoT,
                                                  const float* __restrict__ bias,
                                                  float* __restrict__ out) {
  __shared__ unsigned short As[128 * 64];
  __shared__ unsigned short Bs[128 * 64];
  f32x4 acc[4][4] = {};
  gemm_core_128(Abf, WoT, CC, blockIdx.y * 128, blockIdx.x * 128, As, Bs, acc);
  const int lane = threadIdx.x & 63, w = threadIdx.x >> 6;
  const int m0 = blockIdx.y * 128 + (w >> 1) * 64;
  const int n0 = blockIdx.x * 128 + (w & 1) * 64;
#pragma unroll
  for (int i = 0; i < 4; ++i) {
#pragma unroll
    for (int j = 0; j < 4; ++j) {
      const int n = n0 + j * 16 + (lane & 15);
      const float bv = bias[n];
#pragma unroll
      for (int r = 0; r < 4; ++r) {
        const int m = m0 + i * 16 + (lane >> 4) * 4 + r;
        out[(unsigned)m * CC + n] = acc[i][j][r] + bv;
      }
    }
  }
}

// ---------------- Kernel 2: feature map q' = relu(q @ proj_h)/8 ------------
__global__ __launch_bounds__(256) void k_feat(const float* __restrict__ proj,
                                              float* __restrict__ ws) {
  __shared__ float XsT[64][64];
  __shared__ float Ps[64][64];
  const int tid = threadIdx.x;
  const int t0 = blockIdx.x * 64;
  const int h = blockIdx.y;
  const int which = blockIdx.z;
  const float* src = ws + (which == 0 ? OFF_Q : OFF_K) + (unsigned)h * TT * DD;
  float* dst = ws + (which == 0 ? OFF_QP : OFF_KP) + (unsigned)h * TT * FM;
#pragma unroll
  for (int rep = 0; rep < 4; ++rep) {
    int f = tid + rep * 256;
    int row = f >> 4;
    int q = (f & 15) << 2;
    float4 v = *reinterpret_cast<const float4*>(&src[(t0 + row) * DD + q]);
    XsT[q + 0][row] = v.x; XsT[q + 1][row] = v.y;
    XsT[q + 2][row] = v.z; XsT[q + 3][row] = v.w;
    *reinterpret_cast<float4*>(&Ps[row][q]) =
        *reinterpret_cast<const float4*>(&proj[((unsigned)h * DD + row) * FM + q]);
  }
  __syncthreads();
  const int tx = tid & 15, ty = tid >> 4;
  float acc[4][4] = {};
#pragma unroll 8
  for (int kk = 0; kk < 64; ++kk) {
    float4 a = *reinterpret_cast<const float4*>(&XsT[kk][ty * 4]);
    float4 b = *reinterpret_cast<const float4*>(&Ps[kk][tx * 4]);
    FMA4x4(acc, a, b);
  }
#pragma unroll
  for (int i = 0; i < 4; ++i) {
    int row = t0 + ty * 4 + i;
#pragma unroll
    for (int j = 0; j < 4; ++j) {
      int col = tx * 4 + j;
      float v = acc[i][j];
      v = v > 0.f ? v : 0.f;
      dst[(unsigned)row * FM + col] = v * 0.125f;
    }
  }
}

// ---------------- Kernel 3: per-chunk KV = k'^T @ v, Ksum ------------------
__global__ __launch_bounds__(256) void k_chunkkv(float* __restrict__ ws) {
  __shared__ float Ks[64][64];
  __shared__ float Vs[64][64];
  const int tid = threadIdx.x;
  const int c = blockIdx.x, h = blockIdx.y;
  const int t0 = c * CL;
  const float* kp = ws + OFF_KP + (unsigned)h * TT * FM;
  const float* vv = ws + OFF_V + (unsigned)h * TT * DD;
#pragma unroll
  for (int rep = 0; rep < 4; ++rep) {
    int f = tid + rep * 256;
    int row = f >> 4, q = (f & 15) << 2;
    *reinterpret_cast<float4*>(&Ks[row][q]) =
        *reinterpret_cast<const float4*>(&kp[(t0 + row) * FM + q]);
    *reinterpret_cast<float4*>(&Vs[row][q]) =
        *reinterpret_cast<const float4*>(&vv[(t0 + row) * DD + q]);
  }
  __syncthreads();
  const int tx = tid & 15, ty = tid >> 4;
  float acc[4][4] = {};
#pragma unroll 8
  for (int t = 0; t < 64; ++t) {
    float4 a = *reinterpret_cast<const float4*>(&Ks[t][ty * 4]);
    float4 b = *reinterpret_cast<const float4*>(&Vs[t][tx * 4]);
    FMA4x4(acc, a, b);
  }
  float* kv = ws + OFF_KV + (unsigned)(h * NCH + c) * (FM * DD);
#pragma unroll
  for (int i = 0; i < 4; ++i)
#pragma unroll
    for (int j = 0; j < 4; ++j)
      kv[(unsigned)(ty * 4 + i) * DD + tx * 4 + j] = acc[i][j];
  if (tid < 64) {
    float s = 0.f;
    for (int t = 0; t < 64; ++t) s += Ks[t][tid];
    ws[OFF_KS + (unsigned)(h * NCH + c) * FM + tid] = s;
  }
}

// ---------------- Kernel 4: exclusive prefix over chunks (parallel) --------
// One thread per (h, e) element: 65536 threads, coalesced across e.
__global__ __launch_bounds__(256) void k_prefix(float* __restrict__ ws) {
  const int h = blockIdx.y;
  const unsigned e = blockIdx.x * 256u + threadIdx.x;  // 0..4095
  const unsigned base = (unsigned)h * NCH * 4096u + e;
  float run = 0.f;
#pragma unroll
  for (int c = 0; c < NCH; ++c) {
    const unsigned idx = base + (unsigned)c * 4096u;
    ws[OFF_SPRE + idx] = run;
    run += ws[OFF_KV + idx];
  }
  if (blockIdx.x == 0 && threadIdx.x < 64) {
    const unsigned zbase = (unsigned)h * NCH * 64u + threadIdx.x;
    float zrun = 0.f;
#pragma unroll
    for (int c = 0; c < NCH; ++c) {
      const unsigned idx = zbase + (unsigned)c * 64u;
      ws[OFF_ZPRE + idx] = zrun;
      zrun += ws[OFF_KS + idx];
    }
  }
}

// ---------------- Kernel 5: per-(h,c) intra-chunk attention ----------------
__global__ __launch_bounds__(256) void k_attn(float* __restrict__ ws,
                                              unsigned short* __restrict__ attnb) {
  __shared__ float QT[64][64];
  __shared__ float Vs[64][64];
  __shared__ float Ss[64][64];
  __shared__ float AT[64][64];
  __shared__ float zs[64];
  __shared__ float norm_s[64];
  const int tid = threadIdx.x;
  const int c = blockIdx.x, h = blockIdx.y;
  const int t0 = c * CL;
  const float* qp = ws + OFF_QP + (unsigned)h * TT * FM;
  const float* kp = ws + OFF_KP + (unsigned)h * TT * FM;
  const float* vv = ws + OFF_V + (unsigned)h * TT * DD;
  const float* sp = ws + OFF_SPRE + (unsigned)(h * NCH + c) * 4096u;
  const float* zp = ws + OFF_ZPRE + (unsigned)(h * NCH + c) * 64u;
#pragma unroll
  for (int rep = 0; rep < 4; ++rep) {
    int f = tid + rep * 256;
    int row = f >> 4, q = (f & 15) << 2;
    float4 a = *reinterpret_cast<const float4*>(&qp[(t0 + row) * FM + q]);
    QT[q + 0][row] = a.x; QT[q + 1][row] = a.y;
    QT[q + 2][row] = a.z; QT[q + 3][row] = a.w;
    float4 b = *reinterpret_cast<const float4*>(&kp[(t0 + row) * FM + q]);
    AT[q + 0][row] = b.x; AT[q + 1][row] = b.y;
    AT[q + 2][row] = b.z; AT[q + 3][row] = b.w;
    *reinterpret_cast<float4*>(&Vs[row][q]) =
        *reinterpret_cast<const float4*>(&vv[(t0 + row) * DD + q]);
    *reinterpret_cast<float4*>(&Ss[row][q]) =
        *reinterpret_cast<const float4*>(&sp[row * DD + q]);
  }
  if (tid < 64) zs[tid] = zp[tid];
  __syncthreads();
  const int tx = tid & 15, ty = tid >> 4;
  float accA[4][4] = {};
#pragma unroll 8
  for (int m = 0; m < 64; ++m) {
    float4 a = *reinterpret_cast<const float4*>(&QT[m][ty * 4]);
    float4 b = *reinterpret_cast<const float4*>(&AT[m][tx * 4]);
    FMA4x4(accA, a, b);
  }
  __syncthreads();
#pragma unroll
  for (int i = 0; i < 4; ++i)
#pragma unroll
    for (int j = 0; j < 4; ++j) {
      int row = ty * 4 + i, s = tx * 4 + j;
      AT[s][row] = (s <= row) ? accA[i][j] : 0.f;
    }
  __syncthreads();
  if (tid < 64) {
    int row = tid;
    float nr = 0.f;
    for (int s = 0; s < 64; ++s) nr += AT[s][row];
    float qz = 0.f;
    for (int m = 0; m < 64; ++m) qz += QT[m][row] * zs[m];
    norm_s[row] = nr + qz + EPSV;
  }
  __syncthreads();
  float acc[4][4] = {};
#pragma unroll 8
  for (int m = 0; m < 64; ++m) {
    float4 a = *reinterpret_cast<const float4*>(&QT[m][ty * 4]);
    float4 b = *reinterpret_cast<const float4*>(&Ss[m][tx * 4]);
    FMA4x4(acc, a, b);
  }
#pragma unroll 8
  for (int s = 0; s < 64; ++s) {
    float4 a = *reinterpret_cast<const float4*>(&AT[s][ty * 4]);
    float4 b = *reinterpret_cast<const float4*>(&Vs[s][tx * 4]);
    FMA4x4(acc, a, b);
  }
#pragma unroll
  for (int i = 0; i < 4; ++i) {
    int row = ty * 4 + i;
    float inv = 1.0f / norm_s[row];
#pragma unroll
    for (int j = 0; j < 4; ++j) {
      int d = tx * 4 + j;
      attnb[(unsigned)(t0 + row) * CC + h * DD + d] = f2bf(acc[i][j] * inv);
    }
  }
}

extern "C" void kernel_launch(void* const* d_in, const int* in_sizes, int n_in,
                              void* d_out, int out_size, void* d_ws, size_t ws_size,
                              hipStream_t stream) {
  const float* x = (const float*)d_in[0];
  const float* w_qkv = (const float*)d_in[1];
  const float* b_qkv = (const float*)d_in[2];
  const float* w_out = (const float*)d_in[3];
  const float* b_out = (const float*)d_in[4];
  const float* proj = (const float*)d_in[5];
  float* ws = (float*)d_ws;
  float* out = (float*)d_out;
  unsigned short* xbf = (unsigned short*)(ws + OFF_BF16);
  unsigned short* wqT = xbf + 2097152u;
  unsigned short* woT = wqT + 3145728u;
  unsigned short* attnb = xbf;  // alias: x_bf16 dead after k_qkv_mfma
  dim3 blk(256, 1, 1);
  k_f32_to_bf16<<<dim3(2048), blk, 0, stream>>>(x, xbf);
  k_transpose_bf<<<dim3(N_QKV / 64, CC / 64), blk, 0, stream>>>(w_qkv, wqT, CC, N_QKV);
  k_transpose_bf<<<dim3(CC / 64, CC / 64), blk, 0, stream>>>(w_out, woT, CC, CC);
  k_qkv_mfma<<<dim3(N_QKV / 128, TT / 128), blk, 0, stream>>>(xbf, wqT, b_qkv, ws);
  k_feat<<<dim3(TT / 64, HH, 2), blk, 0, stream>>>(proj, ws);
  k_chunkkv<<<dim3(NCH, HH), blk, 0, stream>>>(ws);
  k_prefix<<<dim3(16, HH), blk, 0, stream>>>(ws);
  k_attn<<<dim3(NCH, HH), blk, 0, stream>>>(ws, attnb);
  k_out_mfma<<<dim3(CC / 128, TT / 128), blk, 0, stream>>>(attnb, woT, b_out, out);
}

// Round 4
// 90.366 us; speedup vs baseline: 3.4397x; 1.1643x over previous
//
#include <hip/hip_runtime.h>
#include <hip/hip_bf16.h>

#define TT 2048
#define CC 1024
#define HH 16
#define DD 64
#define FM 64
#define NCH 32
#define CL 64
#define N_QKV 3072
#define EPSV 1e-6f

// fp32 workspace region (float units)
#define OFF_KVT 0u          // KV^T fp32 [16][32][64d][64m]
#define OFF_KS  2097152u    // Ksum fp32 [16][32][64m]
#define OFF_Z   2129920u    // z fp32 [16][32][64m]
#define OFF_U16 2162688u    // bf16 region start (float units)
// bf16 region offsets (ushort units)
#define U_QBF 0u            // q bf16 [16][2048][64]
#define U_KBF 2097152u      // k bf16 [16][2048][64]
#define U_VT  4194304u      // v^T bf16 [16][64][2048]
#define U_QP  6291456u      // q' bf16 [16][2048][64m]
#define U_KP  8388608u      // k' bf16 [16][2048][64m]
#define U_KPT 10485760u     // k'^T bf16 [16][64m][2048]
#define U_ST  12582912u     // S^T bf16 [16][32][64d][64m]
#define U_XBF 14680064u     // x bf16 (later aliased as attnb)
#define U_WQT 16777216u     // w_qkv^T bf16 [3072][1024]
#define U_WOT 19922944u     // w_out^T bf16 [1024][1024]

typedef __attribute__((ext_vector_type(8))) short bf16x8;
typedef __attribute__((ext_vector_type(4))) float f32x4;
typedef __attribute__((ext_vector_type(4))) unsigned short u16x4;

__device__ __forceinline__ unsigned short f2bf(float f) {
  unsigned int u = __float_as_uint(f);
  u = (u + 0x7fffu + ((u >> 16) & 1u)) >> 16;
  return (unsigned short)u;
}
__device__ __forceinline__ float bf2f(unsigned short b) {
  return __uint_as_float(((unsigned)b) << 16);
}

__device__ __forceinline__ void gload16(const void* g, void* l) {
  __builtin_amdgcn_global_load_lds(
      (const __attribute__((address_space(1))) unsigned int*)g,
      (__attribute__((address_space(3))) unsigned int*)l, 16, 0, 0);
}

// stage a 64-row x 64-ushort (8KB) tile into LDS, XOR-swizzled (chunk^=row&7)
__device__ __forceinline__ void stage_tile64(const unsigned short* g, unsigned rowstride,
                                             unsigned short* lds, int w, int lane) {
  const int l8 = lane >> 3, l7 = lane & 7;
  const int kcg = (l7 ^ l8) * 8;
#pragma unroll
  for (int jj = 0; jj < 2; ++jj) {
    const int inst = w * 2 + jj;
    const int row = inst * 8 + l8;
    gload16(&g[(unsigned)row * rowstride + kcg], &lds[inst * 512]);
  }
}

// read an 8-element bf16 fragment from a swizzled 64x64 LDS tile
__device__ __forceinline__ bf16x8 frag64(const unsigned short* lds, int r, int kchunk) {
  const int slot = kchunk ^ (r & 7);
  return *reinterpret_cast<const bf16x8*>(&lds[r * 64 + slot * 8]);
}

// ---------------- fp32 -> bf16 elementwise (x) -----------------------------
__global__ __launch_bounds__(256) void k_f32_to_bf16(const float* __restrict__ src,
                                                     unsigned short* __restrict__ dst) {
  unsigned i = blockIdx.x * 256u + threadIdx.x;
  float4 v = *reinterpret_cast<const float4*>(&src[i * 4u]);
  u16x4 o;
  o[0] = f2bf(v.x); o[1] = f2bf(v.y); o[2] = f2bf(v.z); o[3] = f2bf(v.w);
  *reinterpret_cast<u16x4*>(&dst[i * 4u]) = o;
}

// ---------------- fp32 [K][N] -> bf16 [N][K] transpose ---------------------
__global__ __launch_bounds__(256) void k_transpose_bf(const float* __restrict__ src,
                                                      unsigned short* __restrict__ dst,
                                                      int K, int N) {
  __shared__ float T[64][68];
  const int tid = threadIdx.x;
  const int n0 = blockIdx.x * 64, k0 = blockIdx.y * 64;
#pragma unroll
  for (int it = 0; it < 4; ++it) {
    int f = tid + it * 256;
    int r = f >> 4, c4 = (f & 15) * 4;
    float4 v = *reinterpret_cast<const float4*>(&src[(unsigned)(k0 + r) * N + n0 + c4]);
    T[r][c4 + 0] = v.x; T[r][c4 + 1] = v.y;
    T[r][c4 + 2] = v.z; T[r][c4 + 3] = v.w;
  }
  __syncthreads();
#pragma unroll
  for (int it = 0; it < 4; ++it) {
    int f = tid + it * 256;
    int nl = f >> 4, kq = (f & 15) * 4;
    u16x4 o;
#pragma unroll
    for (int j = 0; j < 4; ++j) o[j] = f2bf(T[kq + j][nl]);
    *reinterpret_cast<u16x4*>(&dst[(unsigned)(n0 + nl) * K + k0 + kq]) = o;
  }
}

// ---------------- shared 128x128 MFMA GEMM core ----------------------------
__device__ __forceinline__ void gemm_core_128(
    const unsigned short* __restrict__ A, const unsigned short* __restrict__ BT,
    int K, int m0, int n0, unsigned short* As, unsigned short* Bs,
    f32x4 acc[4][4]) {
  const int tid = threadIdx.x;
  const int lane = tid & 63;
  const int w = tid >> 6;
  const int wm = w >> 1, wn = w & 1;
  const int l8 = lane >> 3, l7 = lane & 7;
  const int kcg = (l7 ^ l8) * 8;
  for (int k0 = 0; k0 < K; k0 += 64) {
    if (k0) __syncthreads();
#pragma unroll
    for (int j = 0; j < 4; ++j) {
      const int inst = w * 4 + j;
      const int row = inst * 8 + l8;
      gload16(&A[(unsigned)(m0 + row) * K + k0 + kcg], &As[inst * 512]);
      gload16(&BT[(unsigned)(n0 + row) * K + k0 + kcg], &Bs[inst * 512]);
    }
    __syncthreads();
#pragma unroll
    for (int kk = 0; kk < 2; ++kk) {
      bf16x8 af[4], bg[4];
#pragma unroll
      for (int i = 0; i < 4; ++i) {
        const int r = wm * 64 + i * 16 + (lane & 15);
        const int slot = (kk * 4 + (lane >> 4)) ^ (r & 7);
        af[i] = *reinterpret_cast<const bf16x8*>(&As[r * 64 + slot * 8]);
      }
#pragma unroll
      for (int j = 0; j < 4; ++j) {
        const int r = wn * 64 + j * 16 + (lane & 15);
        const int slot = (kk * 4 + (lane >> 4)) ^ (r & 7);
        bg[j] = *reinterpret_cast<const bf16x8*>(&Bs[r * 64 + slot * 8]);
      }
#pragma unroll
      for (int i = 0; i < 4; ++i)
#pragma unroll
        for (int j = 0; j < 4; ++j)
          acc[i][j] = __builtin_amdgcn_mfma_f32_16x16x32_bf16(af[i], bg[j],
                                                              acc[i][j], 0, 0, 0);
    }
  }
}

// ---------------- Kernel 1: qkv GEMM, scatter q/k bf16, vT bf16 ------------
__global__ __launch_bounds__(256) void k_qkv_mfma(const unsigned short* __restrict__ Xbf,
                                                  const unsigned short* __restrict__ WqT,
                                                  const float* __restrict__ bias,
                                                  unsigned short* __restrict__ qbf,
                                                  unsigned short* __restrict__ kbf,
                                                  unsigned short* __restrict__ vt) {
  __shared__ unsigned short As[128 * 64];
  __shared__ unsigned short Bs[128 * 64];
  f32x4 acc[4][4] = {};
  gemm_core_128(Xbf, WqT, CC, blockIdx.y * 128, blockIdx.x * 128, As, Bs, acc);
  const int lane = threadIdx.x & 63, w = threadIdx.x >> 6;
  const int m0 = blockIdx.y * 128 + (w >> 1) * 64;
  const int n0 = blockIdx.x * 128 + (w & 1) * 64;
#pragma unroll
  for (int i = 0; i < 4; ++i) {
    const int t0 = m0 + i * 16 + (lane >> 4) * 4;
#pragma unroll
    for (int j = 0; j < 4; ++j) {
      const int n = n0 + j * 16 + (lane & 15);
      const float bv = bias[n];
      const int sel = n >> 10, within = n & 1023;
      const int h = within >> 6, d = within & 63;
      if (sel == 2) {
        u16x4 o;
#pragma unroll
        for (int r = 0; r < 4; ++r) o[r] = f2bf(acc[i][j][r] + bv);
        *reinterpret_cast<u16x4*>(&vt[((unsigned)h * 64 + d) * TT + t0]) = o;
      } else {
        unsigned short* dst = (sel ? kbf : qbf) + (unsigned)h * TT * 64 + d;
#pragma unroll
        for (int r = 0; r < 4; ++r)
          dst[(unsigned)(t0 + r) * 64] = f2bf(acc[i][j][r] + bv);
      }
    }
  }
}

// ---------------- Kernel 2: MFMA feature map -------------------------------
// computes p^T[m][t] = sum_d proj[d][m] x[t][d]; relu/8; writes [t][m] (+k'T, Ksum)
__global__ __launch_bounds__(256) void k_feat(const float* __restrict__ proj,
                                              const unsigned short* __restrict__ qbf,
                                              const unsigned short* __restrict__ kbf,
                                              unsigned short* __restrict__ qp,
                                              unsigned short* __restrict__ kp,
                                              unsigned short* __restrict__ kpt,
                                              float* __restrict__ ksum) {
  __shared__ unsigned short Xs[4096];
  __shared__ float Pj[4096];
  __shared__ unsigned short Os[4096];
  const int tid = threadIdx.x, lane = tid & 63, w = tid >> 6;
  const int c = blockIdx.x, h = blockIdx.y, which = blockIdx.z;
  const unsigned short* src = (which ? kbf : qbf) + ((unsigned)h * TT + c * 64) * 64;
  stage_tile64(src, 64, Xs, w, lane);
#pragma unroll
  for (int it = 0; it < 4; ++it) {
    const unsigned idx = (unsigned)(tid + it * 256) * 4u;
    *reinterpret_cast<f32x4*>(&Pj[idx]) =
        *reinterpret_cast<const f32x4*>(&proj[(unsigned)h * 4096 + idx]);
  }
  __syncthreads();
  const int mrow = w * 16 + (lane & 15);
  bf16x8 af[2];
#pragma unroll
  for (int kk = 0; kk < 2; ++kk)
#pragma unroll
    for (int e = 0; e < 8; ++e) {
      const int d = (lane >> 4) * 8 + kk * 32 + e;
      af[kk][e] = (short)f2bf(Pj[d * 64 + mrow]);
    }
  f32x4 accf[4] = {};
#pragma unroll
  for (int j = 0; j < 4; ++j)
#pragma unroll
    for (int kk = 0; kk < 2; ++kk)
      accf[j] = __builtin_amdgcn_mfma_f32_16x16x32_bf16(
          af[kk], frag64(Xs, j * 16 + (lane & 15), kk * 4 + (lane >> 4)), accf[j], 0, 0, 0);
#pragma unroll
  for (int j = 0; j < 4; ++j)
#pragma unroll
    for (int r = 0; r < 4; ++r) {
      float v = accf[j][r];
      accf[j][r] = (v > 0.f ? v : 0.f) * 0.125f;
    }
  // stage p' into Os swizzled as [t][m]
#pragma unroll
  for (int j = 0; j < 4; ++j) {
    const int t = j * 16 + (lane & 15);
#pragma unroll
    for (int r = 0; r < 4; ++r) {
      const int m = w * 16 + (lane >> 4) * 4 + r;
      Os[t * 64 + (((m >> 3) ^ (t & 7)) * 8) + (m & 7)] = f2bf(accf[j][r]);
    }
  }
  if (which) {
    unsigned short* kt = kpt + (unsigned)h * 64 * TT + (unsigned)c * 64;
#pragma unroll
    for (int j = 0; j < 4; ++j) {
      const int t = j * 16 + (lane & 15);
#pragma unroll
      for (int r = 0; r < 4; ++r) {
        const int m = w * 16 + (lane >> 4) * 4 + r;
        kt[(unsigned)m * TT + t] = f2bf(accf[j][r]);
      }
    }
    float rs[4];
#pragma unroll
    for (int r = 0; r < 4; ++r) {
      float s = accf[0][r] + accf[1][r] + accf[2][r] + accf[3][r];
#pragma unroll
      for (int off = 1; off < 16; off <<= 1) s += __shfl_xor(s, off, 64);
      rs[r] = s;
    }
    if ((lane & 15) == 0) {
#pragma unroll
      for (int r = 0; r < 4; ++r) {
        const int m = w * 16 + (lane >> 4) * 4 + r;
        ksum[((unsigned)h * NCH + c) * 64u + m] = rs[r];
      }
    }
  }
  __syncthreads();
  unsigned short* dst = (which ? kp : qp) + ((unsigned)h * TT + c * 64) * 64;
  {
    const int t = tid >> 2;
#pragma unroll
    for (int q = 0; q < 2; ++q) {
      const int chunk = (tid & 3) * 2 + q;
      bf16x8 vle = *reinterpret_cast<const bf16x8*>(&Os[t * 64 + ((chunk ^ (t & 7)) * 8)]);
      *reinterpret_cast<bf16x8*>(&dst[t * 64 + chunk * 8]) = vle;
    }
  }
}

// ---------------- Kernel 3: KV^T[d][m] = sum_t k'[t][m] v[t][d] (MFMA) -----
__global__ __launch_bounds__(256) void k_chunkkv(const unsigned short* __restrict__ kpt,
                                                 const unsigned short* __restrict__ vt,
                                                 float* __restrict__ kvt) {
  __shared__ unsigned short KTs[4096];
  __shared__ unsigned short VTs[4096];
  const int tid = threadIdx.x, lane = tid & 63, w = tid >> 6;
  const int c = blockIdx.x, h = blockIdx.y;
  stage_tile64(kpt + (unsigned)h * 64 * TT + (unsigned)c * 64, TT, KTs, w, lane);
  stage_tile64(vt + (unsigned)h * 64 * TT + (unsigned)c * 64, TT, VTs, w, lane);
  __syncthreads();
  const int mr = w * 16 + (lane & 15);
  bf16x8 af[2];
#pragma unroll
  for (int kk = 0; kk < 2; ++kk) af[kk] = frag64(KTs, mr, kk * 4 + (lane >> 4));
  f32x4 acc[4] = {};
#pragma unroll
  for (int j = 0; j < 4; ++j)
#pragma unroll
    for (int kk = 0; kk < 2; ++kk)
      acc[j] = __builtin_amdgcn_mfma_f32_16x16x32_bf16(
          af[kk], frag64(VTs, j * 16 + (lane & 15), kk * 4 + (lane >> 4)), acc[j], 0, 0, 0);
  float* dst = kvt + ((unsigned)h * NCH + c) * 4096u;
#pragma unroll
  for (int j = 0; j < 4; ++j) {
    const int d = j * 16 + (lane & 15);
    const int mq = w * 16 + (lane >> 4) * 4;
    *reinterpret_cast<f32x4*>(&dst[(unsigned)d * 64 + mq]) = acc[j];
  }
}

// ---------------- Kernel 4: exclusive prefix over chunks (parallel) --------
__global__ __launch_bounds__(256) void k_prefix(const float* __restrict__ kvt,
                                                const float* __restrict__ ksum,
                                                unsigned short* __restrict__ st,
                                                float* __restrict__ z) {
  const int h = blockIdx.y;
  const unsigned e = blockIdx.x * 256u + threadIdx.x;
  float run = 0.f;
#pragma unroll
  for (int c = 0; c < NCH; ++c) {
    const unsigned idx = ((unsigned)h * NCH + c) * 4096u + e;
    st[idx] = f2bf(run);
    run += kvt[idx];
  }
  if (blockIdx.x == 0 && threadIdx.x < 64) {
    float zr = 0.f;
#pragma unroll
    for (int c = 0; c < NCH; ++c) {
      const unsigned idx = ((unsigned)h * NCH + c) * 64u + threadIdx.x;
      z[idx] = zr;
      zr += ksum[idx];
    }
  }
}

// ---------------- Kernel 5: per-(h,c) intra-chunk attention (MFMA) ---------
__global__ __launch_bounds__(256) void k_attn(const unsigned short* __restrict__ qp,
                                              const unsigned short* __restrict__ kp,
                                              const unsigned short* __restrict__ vt,
                                              const unsigned short* __restrict__ st,
                                              const float* __restrict__ z,
                                              unsigned short* __restrict__ attnb) {
  __shared__ unsigned short QPs[4096];
  __shared__ unsigned short KPs[4096];  // reused as A^bf16 after phase A
  __shared__ unsigned short VTs[4096];
  __shared__ unsigned short STs[4096];
  __shared__ float zsm[64];
  __shared__ float nsm[64];
  const int tid = threadIdx.x, lane = tid & 63, w = tid >> 6;
  const int c = blockIdx.x, h = blockIdx.y;
  stage_tile64(qp + ((unsigned)h * TT + c * 64) * 64, 64, QPs, w, lane);
  stage_tile64(kp + ((unsigned)h * TT + c * 64) * 64, 64, KPs, w, lane);
  stage_tile64(vt + (unsigned)h * 64 * TT + (unsigned)c * 64, TT, VTs, w, lane);
  stage_tile64(st + ((unsigned)h * NCH + c) * 4096u, 64, STs, w, lane);
  if (tid < 64) zsm[tid] = z[((unsigned)h * NCH + c) * 64u + tid];
  __syncthreads();
  // phase A: A[t][s] = q'[t]·k'[s]
  const int tr = w * 16 + (lane & 15);
  bf16x8 afq[2];
#pragma unroll
  for (int kk = 0; kk < 2; ++kk) afq[kk] = frag64(QPs, tr, kk * 4 + (lane >> 4));
  f32x4 accA[4] = {};
#pragma unroll
  for (int j = 0; j < 4; ++j)
#pragma unroll
    for (int kk = 0; kk < 2; ++kk)
      accA[j] = __builtin_amdgcn_mfma_f32_16x16x32_bf16(
          afq[kk], frag64(KPs, j * 16 + (lane & 15), kk * 4 + (lane >> 4)), accA[j], 0, 0, 0);
  // causal mask + fp32 rowsum
  float rs[4] = {0.f, 0.f, 0.f, 0.f};
#pragma unroll
  for (int j = 0; j < 4; ++j) {
    const int s = j * 16 + (lane & 15);
#pragma unroll
    for (int r = 0; r < 4; ++r) {
      const int t = w * 16 + (lane >> 4) * 4 + r;
      float v = (s <= t) ? accA[j][r] : 0.f;
      accA[j][r] = v;
      rs[r] += v;
    }
  }
#pragma unroll
  for (int r = 0; r < 4; ++r)
#pragma unroll
    for (int off = 1; off < 16; off <<= 1) rs[r] += __shfl_xor(rs[r], off, 64);
  __syncthreads();  // all phase-A reads of KPs done
  if ((lane & 15) == 0) {
#pragma unroll
    for (int r = 0; r < 4; ++r) nsm[w * 16 + (lane >> 4) * 4 + r] = rs[r];
  }
  // write masked A (bf16, swizzled) into KPs
#pragma unroll
  for (int j = 0; j < 4; ++j) {
    const int s = j * 16 + (lane & 15);
#pragma unroll
    for (int r = 0; r < 4; ++r) {
      const int t = w * 16 + (lane >> 4) * 4 + r;
      KPs[t * 64 + (((s >> 3) ^ (t & 7)) * 8) + (s & 7)] = f2bf(accA[j][r]);
    }
  }
  __syncthreads();
  // qz: nsm[t] += q'[t]·z + EPS
  {
    const int t = tid >> 2, part = tid & 3;
    float qz = 0.f;
#pragma unroll
    for (int mm = 0; mm < 16; ++mm) {
      const int m = part * 16 + mm;
      qz += bf2f(QPs[t * 64 + (((m >> 3) ^ (t & 7)) * 8) + (m & 7)]) * zsm[m];
    }
    qz += __shfl_xor(qz, 1, 64);
    qz += __shfl_xor(qz, 2, 64);
    if (part == 0) nsm[t] += qz + EPSV;
  }
  // phase B: ctx[t][d] = A@vT + q'@S^T
  bf16x8 afa[2];
#pragma unroll
  for (int kk = 0; kk < 2; ++kk) afa[kk] = frag64(KPs, tr, kk * 4 + (lane >> 4));
  f32x4 acc[4] = {};
#pragma unroll
  for (int j = 0; j < 4; ++j) {
    const int br = j * 16 + (lane & 15);
#pragma unroll
    for (int kk = 0; kk < 2; ++kk) {
      acc[j] = __builtin_amdgcn_mfma_f32_16x16x32_bf16(
          afa[kk], frag64(VTs, br, kk * 4 + (lane >> 4)), acc[j], 0, 0, 0);
      acc[j] = __builtin_amdgcn_mfma_f32_16x16x32_bf16(
          afq[kk], frag64(STs, br, kk * 4 + (lane >> 4)), acc[j], 0, 0, 0);
    }
  }
  __syncthreads();  // nsm finalized
#pragma unroll
  for (int j = 0; j < 4; ++j) {
    const int d = j * 16 + (lane & 15);
#pragma unroll
    for (int r = 0; r < 4; ++r) {
      const int t = w * 16 + (lane >> 4) * 4 + r;
      attnb[(unsigned)(c * 64 + t) * CC + h * 64 + d] = f2bf(acc[j][r] / nsm[t]);
    }
  }
}

// ---------------- Kernel 6: out = attn @ w_out + b (MFMA) ------------------
__global__ __launch_bounds__(256) void k_out_mfma(const unsigned short* __restrict__ Abf,
                                                  const unsigned short* __restrict__ WoT,
                                                  const float* __restrict__ bias,
                                                  float* __restrict__ out) {
  __shared__ unsigned short As[128 * 64];
  __shared__ unsigned short Bs[128 * 64];
  f32x4 acc[4][4] = {};
  gemm_core_128(Abf, WoT, CC, blockIdx.y * 128, blockIdx.x * 128, As, Bs, acc);
  const int lane = threadIdx.x & 63, w = threadIdx.x >> 6;
  const int m0 = blockIdx.y * 128 + (w >> 1) * 64;
  const int n0 = blockIdx.x * 128 + (w & 1) * 64;
#pragma unroll
  for (int i = 0; i < 4; ++i) {
#pragma unroll
    for (int j = 0; j < 4; ++j) {
      const int n = n0 + j * 16 + (lane & 15);
      const float bv = bias[n];
#pragma unroll
      for (int r = 0; r < 4; ++r) {
        const int m = m0 + i * 16 + (lane >> 4) * 4 + r;
        out[(unsigned)m * CC + n] = acc[i][j][r] + bv;
      }
    }
  }
}

extern "C" void kernel_launch(void* const* d_in, const int* in_sizes, int n_in,
                              void* d_out, int out_size, void* d_ws, size_t ws_size,
                              hipStream_t stream) {
  const float* x = (const float*)d_in[0];
  const float* w_qkv = (const float*)d_in[1];
  const float* b_qkv = (const float*)d_in[2];
  const float* w_out = (const float*)d_in[3];
  const float* b_out = (const float*)d_in[4];
  const float* proj = (const float*)d_in[5];
  float* ws = (float*)d_ws;
  float* out = (float*)d_out;
  float* kvt = ws + OFF_KVT;
  float* ksum = ws + OFF_KS;
  float* zf = ws + OFF_Z;
  unsigned short* ub = (unsigned short*)(ws + OFF_U16);
  unsigned short* qbf = ub + U_QBF;
  unsigned short* kbf = ub + U_KBF;
  unsigned short* vt = ub + U_VT;
  unsigned short* qp = ub + U_QP;
  unsigned short* kp = ub + U_KP;
  unsigned short* kpt = ub + U_KPT;
  unsigned short* st = ub + U_ST;
  unsigned short* xbf = ub + U_XBF;
  unsigned short* wqT = ub + U_WQT;
  unsigned short* woT = ub + U_WOT;
  unsigned short* attnb = xbf;  // alias: x_bf16 dead after k_qkv_mfma
  dim3 blk(256, 1, 1);
  k_f32_to_bf16<<<dim3(2048), blk, 0, stream>>>(x, xbf);
  k_transpose_bf<<<dim3(N_QKV / 64, CC / 64), blk, 0, stream>>>(w_qkv, wqT, CC, N_QKV);
  k_transpose_bf<<<dim3(CC / 64, CC / 64), blk, 0, stream>>>(w_out, woT, CC, CC);
  k_qkv_mfma<<<dim3(N_QKV / 128, TT / 128), blk, 0, stream>>>(xbf, wqT, b_qkv, qbf, kbf, vt);
  k_feat<<<dim3(NCH, HH, 2), blk, 0, stream>>>(proj, qbf, kbf, qp, kp, kpt, ksum);
  k_chunkkv<<<dim3(NCH, HH), blk, 0, stream>>>(kpt, vt, kvt);
  k_prefix<<<dim3(16, HH), blk, 0, stream>>>(kvt, ksum, st, zf);
  k_attn<<<dim3(NCH, HH), blk, 0, stream>>>(qp, kp, vt, st, zf, attnb);
  k_out_mfma<<<dim3(CC / 128, TT / 128), blk, 0, stream>>>(attnb, woT, b_out, out);
}